// Round 16
// baseline (304.032 us; speedup 1.0000x reference)
//
#include <hip/hip_runtime.h>
#include <hip/hip_bf16.h>

typedef __attribute__((ext_vector_type(4)))  int   i32x4;
typedef __attribute__((ext_vector_type(16))) int   i32x16;
typedef __attribute__((ext_vector_type(16))) float f32x16;
typedef __attribute__((ext_vector_type(8)))  short short8;

#define SC1 (1.0f/4096.0f)     // xh*wh scale: (1/16)*(1/256)
#define SC2 (1.0f/524288.0f)   // cross terms: (1/16)*(1/32768) == (1/2048)*(1/256)

static __device__ __forceinline__ float ftanh(float x) {
  float e = __builtin_amdgcn_exp2f(x * 2.885390081777927f);
  return 1.0f - 2.0f * __builtin_amdgcn_rcpf(e + 1.0f);
}
static __device__ __forceinline__ unsigned short bf16_rn(float f) {
  unsigned u = __float_as_uint(f);
  u += 0x7FFFu + ((u >> 16) & 1u);
  return (unsigned short)(u >> 16);
}
// x ~= hi/sc + lo/(sc*losc); rne via magic-add. Proven round 6.
static __device__ __forceinline__ void quant2(float x, float sc, float inv, float losc,
                                              int& hi, int& lo) {
  float t  = __builtin_fmaf(x, sc, 12582912.0f);
  hi = __float_as_int(t) - 0x4B400000;
  float hf = t - 12582912.0f;
  float r  = __builtin_fmaf(hf, -inv, x);
  float t2 = __builtin_fmaf(r, losc, 12582912.0f);
  lo = __float_as_int(t2) - 0x4B400000;
}
#define MFMA_I8(ACC, A, B) \
  asm("v_mfma_i32_32x32x32_i8 %0, %1, %2, %0" : "+v"(ACC) : "v"(A), "v"(B))

// ---------------------------------------------------------------------------
// prep_w (verbatim round 6): pack W into chunked fragment streams.
// B1 per chunk kc (64KB): [Q-hi 16KB][Q-lo 16KB][V-bf16 32KB]
//   Q: byte = kc*65536 + sel*16384 + (nt*64+lane)*16 + j
//      value W[col = nt*32+(lane&31)][k = kc*32+(lane>>5)*16+j]
//   V: byte = kc*65536 + 32768 + ((nt*2+ks)*64+lane)*16 + j*2 (8 bf16)
// B2 per chunk (32KB): [K-hi 16KB][K-lo 16KB], same scheme.
// ---------------------------------------------------------------------------
__global__ void prep_w(const float* __restrict__ Wq, const float* __restrict__ Wk,
                       const float* __restrict__ Wv,
                       char* __restrict__ B1, char* __restrict__ B2) {
  int gid = blockIdx.x * 256 + threadIdx.x;   // 0..98303
  if (gid < 65536) {
    int chunk = gid >> 12, g = gid & 4095;
    char* dst = B1 + chunk * 65536 + g * 16;
    if (g < 2048) {
      int sel = g >> 10;
      int gg = g & 1023, nt = gg >> 6, lane = gg & 63;
      const float* src = Wq + (size_t)(nt * 32 + (lane & 31)) * 512 + chunk * 32 + (lane >> 5) * 16;
      union { char b[16]; i32x4 v; } ob;
#pragma unroll
      for (int j = 0; j < 16; ++j) {
        int h, l; quant2(src[j], 256.f, 1.f / 256.f, 32768.f, h, l);
        ob.b[j] = (char)(sel ? l : h);
      }
      *(i32x4*)dst = ob.v;
    } else {
      int gg = g - 2048, nt = gg >> 7, ks = (gg >> 6) & 1, lane = gg & 63;
      const float* src = Wv + (size_t)(nt * 32 + (lane & 31)) * 512 + chunk * 32 + ks * 16 + (lane >> 5) * 8;
      union { unsigned short s[8]; i32x4 v; } ob;
#pragma unroll
      for (int j = 0; j < 8; ++j) ob.s[j] = bf16_rn(src[j]);
      *(i32x4*)dst = ob.v;
    }
  } else {
    int gid2 = gid - 65536;
    int chunk = gid2 >> 11, g = gid2 & 2047;
    char* dst = B2 + chunk * 32768 + g * 16;
    int sel = g >> 10, gg = g & 1023, nt = gg >> 6, lane = gg & 63;
    const float* src = Wk + (size_t)(nt * 32 + (lane & 31)) * 512 + chunk * 32 + (lane >> 5) * 16;
    union { char b[16]; i32x4 v; } ob;
#pragma unroll
    for (int j = 0; j < 16; ++j) {
      int h, l; quant2(src[j], 256.f, 1.f / 256.f, 32768.f, h, l);
      ob.b[j] = (char)(sel ? l : h);
    }
    *(i32x4*)dst = ob.v;
  }
}

// ---- A-staging (verbatim R6/R14): thread (row=tid>>3, d0=(tid&7)*4), 64x32
// chunk -> i8 hi/lo frag planes (4KB: hi mt0@0, mt1@1024; lo @2048/3072). ----
static __device__ __forceinline__ void stageAi8(char* Ab, int row, int d0, float4 xv) {
  const int mt = row >> 5, l31 = row & 31;
  int h0, l0, h1, l1, h2, l2, h3, l3;
  quant2(xv.x, 16.f, 0.0625f, 2048.f, h0, l0);
  quant2(xv.y, 16.f, 0.0625f, 2048.f, h1, l1);
  quant2(xv.z, 16.f, 0.0625f, 2048.f, h2, l2);
  quant2(xv.w, 16.f, 0.0625f, 2048.f, h3, l3);
  unsigned wh = (h0 & 255) | ((h1 & 255) << 8) | ((h2 & 255) << 16) | ((unsigned)(h3 & 255) << 24);
  unsigned wl = (l0 & 255) | ((l1 & 255) << 8) | ((l2 & 255) << 16) | ((unsigned)(l3 & 255) << 24);
  const int lane8 = (d0 >> 4) * 32 + l31, j = d0 & 15;
  *(unsigned*)(Ab + (mt * 64 + lane8) * 16 + j) = wh;
  *(unsigned*)(Ab + 2048 + (mt * 64 + lane8) * 16 + j) = wl;
}
// bf16 (V) frag planes (4KB, (mt*2+ks) planes) -- verbatim R6/R14 stageAv.
static __device__ __forceinline__ void stageAv(char* Ab, int row, int d0, float4 xv) {
  const int mt = row >> 5, l31 = row & 31;
  unsigned long long b0 = bf16_rn(xv.x), b1 = bf16_rn(xv.y), b2 = bf16_rn(xv.z), b3 = bf16_rn(xv.w);
  unsigned long long vv = b0 | (b1 << 16) | (b2 << 32) | (b3 << 48);
  const int ks = d0 >> 4, rem = d0 & 15, hs8 = rem >> 3, j8 = rem & 7;
  *(unsigned long long*)(Ab + ((mt * 2 + ks) * 64 + hs8 * 32 + l31) * 16 + j8 * 2) = vv;
}

// ---------------------------------------------------------------------------
// pass_q: Q (i8 2-term, colsum). 512 thr = 8 waves; block = (ch, rep):
// wave w owns cols of nt = ch*8+w (32 cols), held in REGISTERS (Whi/Wlo[16],
// byte-identical to what R14's gll16+LDS chain delivered). rep covers 4
// sequential 64-row tiles (batch-aligned). A staged via R6-verbatim stageAi8
// into 2x4KB LDS dbuf, one __syncthreads per chunk. No async ops.
// ---------------------------------------------------------------------------
__global__ __launch_bounds__(512, 2) void pass_q(
    const float* __restrict__ x, const char* __restrict__ B1,
    const float* __restrict__ bq, float* __restrict__ qpart) {
  __shared__ char Ab0[4096], Ab1[4096];

  const int tid = threadIdx.x, lane = tid & 63, w = tid >> 6;
  const int l31 = lane & 31;
  const int ch = blockIdx.x & 1, rep = blockIdx.x >> 1;   // rep 0..255
  const int nt = ch * 8 + w;
  const int row = tid >> 3, d0 = (tid & 7) * 4;
  const int lo16 = lane * 16;

  // W slice preload: same bytes R14 read via LDS copy of B1
  i32x4 Whi[16], Wlo[16];
#pragma unroll
  for (int kc = 0; kc < 16; ++kc) {
    const char* wp = B1 + (size_t)kc * 65536 + nt * 1024 + lo16;
    Whi[kc] = *(const i32x4*)(wp);
    Wlo[kc] = *(const i32x4*)(wp + 16384);
  }
  const float bqc = bq[nt * 32 + l31];
  float cs = 0.f;

#pragma unroll 1
  for (int tt = 0; tt < 4; ++tt) {
    const size_t tile = (size_t)rep * 4 + tt;
    const float* gxr = x + (tile * 64 + row) * 512 + d0;

    i32x16 q1[2] = {}, q2[2] = {};
    float4 xcur = *(const float4*)(gxr);
    stageAi8(Ab0, row, d0, xcur);                 // chunk 0
    xcur = *(const float4*)(gxr + 32);            // chunk 1 in regs

#pragma unroll
    for (int c = 0; c < 16; ++c) {
      __syncthreads();
      float4 xnext = xcur;
      if (c < 14) xnext = *(const float4*)(gxr + (c + 2) * 32);
      if (c < 15) stageAi8((c & 1) ? Ab0 : Ab1, row, d0, xcur);   // chunk c+1
      const char* Ac = (c & 1) ? Ab1 : Ab0;                       // chunk c
      i32x4 ah0 = *(const i32x4*)(Ac + lo16);
      i32x4 ah1 = *(const i32x4*)(Ac + 1024 + lo16);
      i32x4 al0 = *(const i32x4*)(Ac + 2048 + lo16);
      i32x4 al1 = *(const i32x4*)(Ac + 3072 + lo16);
      MFMA_I8(q1[0], ah0, Whi[c]);
      MFMA_I8(q2[0], ah0, Wlo[c]);
      MFMA_I8(q2[0], al0, Whi[c]);
      MFMA_I8(q1[1], ah1, Whi[c]);
      MFMA_I8(q2[1], ah1, Wlo[c]);
      MFMA_I8(q2[1], al1, Whi[c]);
      xcur = xnext;
    }
    // per-tile colsum (register-only epilogue; verbatim R14 formula)
#pragma unroll
    for (int mt = 0; mt < 2; ++mt)
#pragma unroll
      for (int r = 0; r < 16; ++r)
        cs += ftanh(__builtin_fmaf((float)q1[mt][r], SC1,
                    __builtin_fmaf((float)q2[mt][r], SC2, bqc)));
  }
  cs += __shfl_xor(cs, 32);
  if (lane < 32) qpart[(size_t)rep * 512 + nt * 32 + l31] = cs;
}

// ---------------------------------------------------------------------------
// pass_v: V (bf16 1-term, rowsum), W-in-registers (32 short8 = wave's 32-col
// slice of the B1 V region; byte-identical to R14's LDS chain). Per-tile
// rowsum partials -> vpart plane [ch].
// ---------------------------------------------------------------------------
__global__ __launch_bounds__(512, 2) void pass_v(
    const float* __restrict__ x, const char* __restrict__ B1,
    const float* __restrict__ bv, float* __restrict__ vpart) {
  __shared__ char Ab0[4096], Ab1[4096];
  __shared__ float redv[8][64];

  const int tid = threadIdx.x, lane = tid & 63, w = tid >> 6;
  const int l31 = lane & 31, hs = lane >> 5;
  const int ch = blockIdx.x & 1, rep = blockIdx.x >> 1;
  const int nt = ch * 8 + w;
  const int row = tid >> 3, d0 = (tid & 7) * 4;
  const int lo16 = lane * 16;

  short8 Wv[32];
#pragma unroll
  for (int kc = 0; kc < 16; ++kc) {
    const char* wp = B1 + (size_t)kc * 65536 + 32768 + (nt * 2) * 1024 + lo16;
    Wv[kc * 2]     = *(const short8*)(wp);
    Wv[kc * 2 + 1] = *(const short8*)(wp + 1024);
  }
  const float bvc = bv[nt * 32 + l31];

#pragma unroll 1
  for (int tt = 0; tt < 4; ++tt) {
    const size_t tile = (size_t)rep * 4 + tt;
    const float* gxr = x + (tile * 64 + row) * 512 + d0;

    f32x16 accv[2] = {};
    float4 xcur = *(const float4*)(gxr);
    stageAv(Ab0, row, d0, xcur);
    xcur = *(const float4*)(gxr + 32);

#pragma unroll
    for (int c = 0; c < 16; ++c) {
      __syncthreads();
      float4 xnext = xcur;
      if (c < 14) xnext = *(const float4*)(gxr + (c + 2) * 32);
      if (c < 15) stageAv((c & 1) ? Ab0 : Ab1, row, d0, xcur);
      const char* Ac = (c & 1) ? Ab1 : Ab0;
      short8 a00 = *(const short8*)(Ac + 0 * 1024 + lo16);   // mt0 ks0
      short8 a01 = *(const short8*)(Ac + 1 * 1024 + lo16);   // mt0 ks1
      short8 a10 = *(const short8*)(Ac + 2 * 1024 + lo16);   // mt1 ks0
      short8 a11 = *(const short8*)(Ac + 3 * 1024 + lo16);   // mt1 ks1
      accv[0] = __builtin_amdgcn_mfma_f32_32x32x16_bf16(a00, Wv[c * 2], accv[0], 0, 0, 0);
      accv[0] = __builtin_amdgcn_mfma_f32_32x32x16_bf16(a01, Wv[c * 2 + 1], accv[0], 0, 0, 0);
      accv[1] = __builtin_amdgcn_mfma_f32_32x32x16_bf16(a10, Wv[c * 2], accv[1], 0, 0, 0);
      accv[1] = __builtin_amdgcn_mfma_f32_32x32x16_bf16(a11, Wv[c * 2 + 1], accv[1], 0, 0, 0);
      xcur = xnext;
    }
    // per-tile rowsum over wave's 32 cols, fold 8 waves (R14 epilogue form)
#pragma unroll
    for (int mt = 0; mt < 2; ++mt)
#pragma unroll
      for (int r = 0; r < 16; ++r) {
        float s = ftanh(accv[mt][r] + bvc);
#pragma unroll
        for (int off = 1; off <= 16; off <<= 1) s += __shfl_xor(s, off);
        if (l31 == 0) redv[w][mt * 32 + (r & 3) + 8 * (r >> 2) + 4 * hs] = s;
      }
    __syncthreads();
    if (tid < 64) {
      float s = 0.f;
#pragma unroll
      for (int j = 0; j < 8; ++j) s += redv[j][tid];
      vpart[(size_t)ch * 65536 + tile * 64 + tid] = s;
    }
  }
}

// ---------------------------------------------------------------------------
// pass_k: K (i8 2-term, rowsum * q_sum), W-in-registers from B2. Partials ->
// spart plane [ch]. rep batch-aligned (b = rep>>4) so qs loads once.
// ---------------------------------------------------------------------------
__global__ __launch_bounds__(512, 2) void pass_k(
    const float* __restrict__ x, const char* __restrict__ B2,
    const float* __restrict__ bk, const float* __restrict__ q_sum,
    float* __restrict__ spart) {
  __shared__ char Ab0[4096], Ab1[4096];
  __shared__ float redk[8][64];

  const int tid = threadIdx.x, lane = tid & 63, w = tid >> 6;
  const int l31 = lane & 31, hs = lane >> 5;
  const int ch = blockIdx.x & 1, rep = blockIdx.x >> 1;
  const int nt = ch * 8 + w;
  const int row = tid >> 3, d0 = (tid & 7) * 4;
  const int lo16 = lane * 16;
  const int b = rep >> 4;   // 16 reps (64 tiles) per batch

  i32x4 Whi[16], Wlo[16];
#pragma unroll
  for (int kc = 0; kc < 16; ++kc) {
    const char* wp = B2 + (size_t)kc * 32768 + nt * 1024 + lo16;
    Whi[kc] = *(const i32x4*)(wp);
    Wlo[kc] = *(const i32x4*)(wp + 16384);
  }
  const float bkc = bk[nt * 32 + l31];
  const float qs = q_sum[b * 512 + nt * 32 + l31];

#pragma unroll 1
  for (int tt = 0; tt < 4; ++tt) {
    const size_t tile = (size_t)rep * 4 + tt;
    const float* gxr = x + (tile * 64 + row) * 512 + d0;

    i32x16 k1[2] = {}, k2[2] = {};
    float4 xcur = *(const float4*)(gxr);
    stageAi8(Ab0, row, d0, xcur);
    xcur = *(const float4*)(gxr + 32);

#pragma unroll
    for (int c = 0; c < 16; ++c) {
      __syncthreads();
      float4 xnext = xcur;
      if (c < 14) xnext = *(const float4*)(gxr + (c + 2) * 32);
      if (c < 15) stageAi8((c & 1) ? Ab0 : Ab1, row, d0, xcur);
      const char* Ac = (c & 1) ? Ab1 : Ab0;
      i32x4 ah0 = *(const i32x4*)(Ac + lo16);
      i32x4 ah1 = *(const i32x4*)(Ac + 1024 + lo16);
      i32x4 al0 = *(const i32x4*)(Ac + 2048 + lo16);
      i32x4 al1 = *(const i32x4*)(Ac + 3072 + lo16);
      MFMA_I8(k1[0], ah0, Whi[c]);
      MFMA_I8(k2[0], ah0, Wlo[c]);
      MFMA_I8(k2[0], al0, Whi[c]);
      MFMA_I8(k1[1], ah1, Whi[c]);
      MFMA_I8(k2[1], ah1, Wlo[c]);
      MFMA_I8(k2[1], al1, Whi[c]);
      xcur = xnext;
    }
    // per-tile rowsum * qs over wave's 32 cols, fold 8 waves
#pragma unroll
    for (int mt = 0; mt < 2; ++mt)
#pragma unroll
      for (int r = 0; r < 16; ++r) {
        float pre = __builtin_fmaf((float)k1[mt][r], SC1,
                    __builtin_fmaf((float)k2[mt][r], SC2, bkc));
        float s = ftanh(pre) * qs;
#pragma unroll
        for (int off = 1; off <= 16; off <<= 1) s += __shfl_xor(s, off);
        if (l31 == 0) redk[w][mt * 32 + (r & 3) + 8 * (r >> 2) + 4 * hs] = s;
      }
    __syncthreads();
    if (tid < 64) {
      float s = 0.f;
#pragma unroll
      for (int j = 0; j < 8; ++j) s += redk[j][tid];
      spart[(size_t)ch * 65536 + tile * 64 + tid] = s;
    }
  }
}

// q_sum[b][e] = sum of the batch's 16 rep partials (each = 4 tiles)
__global__ void reduce_q(const float* __restrict__ qpart, float* __restrict__ q_sum) {
  int b = blockIdx.x, e = threadIdx.x;
  const float* p = qpart + (size_t)b * 16 * 512 + e;
  float s = 0.f;
#pragma unroll
  for (int j = 0; j < 16; ++j) s += p[j * 512];
  q_sum[b * 512 + e] = s;
}

// per-batch masked softmax over scaled scores (2 planes), times sv (2 planes)
__global__ void softmax_out(const float* __restrict__ spart,
                            const float* __restrict__ vpart,
                            const int* __restrict__ lens,
                            float* __restrict__ out) {
  const int b = blockIdx.x, tid = threadIdx.x;   // 256
  const int lane = tid & 63, wid = tid >> 6;
  const int len = lens[b];
  const float scale = 0.04419417382415922f;      // 1/sqrt(512)
  __shared__ float sb[4], sb2[4];

  float sreg[16], svreg[16];
#pragma unroll
  for (int j = 0; j < 16; ++j) {
    size_t l = (size_t)b * 4096 + tid + j * 256;
    sreg[j] = (spart[l] + spart[65536 + l]) * scale;
    svreg[j] = vpart[l] + vpart[65536 + l];
  }

  float m = -1e30f;
#pragma unroll
  for (int j = 0; j < 16; ++j)
    if (tid + j * 256 < len) m = fmaxf(m, sreg[j]);
#pragma unroll
  for (int off = 32; off >= 1; off >>= 1) m = fmaxf(m, __shfl_xor(m, off));
  if (lane == 0) sb[wid] = m;
  __syncthreads();
  m = fmaxf(fmaxf(sb[0], sb[1]), fmaxf(sb[2], sb[3]));

  float s = 0.f;
#pragma unroll
  for (int j = 0; j < 16; ++j)
    if (tid + j * 256 < len) s += expf(sreg[j] - m);
#pragma unroll
  for (int off = 32; off >= 1; off >>= 1) s += __shfl_xor(s, off);
  if (lane == 0) sb2[wid] = s;
  __syncthreads();
  const float inv = 1.f / (sb2[0] + sb2[1] + sb2[2] + sb2[3]);

  float* ob = out + (size_t)b * 4096;
#pragma unroll
  for (int j = 0; j < 16; ++j) {
    int l = tid + j * 256;
    ob[l] = (l < len) ? svreg[j] * expf(sreg[j] - m) * inv : 0.0f;
  }
}

extern "C" void kernel_launch(void* const* d_in, const int* in_sizes, int n_in,
                              void* d_out, int out_size, void* d_ws, size_t ws_size,
                              hipStream_t stream) {
  const float* x  = (const float*)d_in[0];
  const float* Wk = (const float*)d_in[1];
  const float* bk = (const float*)d_in[2];
  const float* Wq = (const float*)d_in[3];
  const float* bq = (const float*)d_in[4];
  const float* Wv = (const float*)d_in[5];
  const float* bv = (const float*)d_in[6];
  const int* lens = (const int*)d_in[7];
  float* out = (float*)d_out;

  char* ws = (char*)d_ws;
  char*  B1     = ws;                          // 1 MB   (Q+V W pack)
  char*  B2     = ws + 1048576;                // 512 KB (K W pack)
  float* qpart  = (float*)(ws + 1572864);      // [256][512] f32 = 512 KB
  float* q_sum  = (float*)(ws + 2097152);      // [16][512] = 32 KB
  float* vpart  = (float*)(ws + 2129920);      // [2][65536] = 512 KB
  float* spart  = (float*)(ws + 2654208);      // [2][65536] = 512 KB

  prep_w<<<384, 256, 0, stream>>>(Wq, Wk, Wv, B1, B2);
  pass_q<<<512, 512, 0, stream>>>(x, B1, bq, qpart);
  pass_v<<<512, 512, 0, stream>>>(x, B1, bv, vpart);
  reduce_q<<<16, 512, 0, stream>>>(qpart, q_sum);
  pass_k<<<512, 512, 0, stream>>>(x, B2, bk, q_sum, spart);
  softmax_out<<<16, 256, 0, stream>>>(spart, vpart, lens, out);
}

// Round 18
// 228.456 us; speedup vs baseline: 1.3308x; 1.3308x over previous
//
#include <hip/hip_runtime.h>
#include <hip/hip_bf16.h>

typedef __attribute__((ext_vector_type(4)))  int   i32x4;
typedef __attribute__((ext_vector_type(16))) int   i32x16;
typedef __attribute__((ext_vector_type(16))) float f32x16;
typedef __attribute__((ext_vector_type(8)))  short short8;

#define SC1 (1.0f/4096.0f)     // xh*wh scale: (1/16)*(1/256)
#define SC2 (1.0f/524288.0f)   // cross terms: (1/16)*(1/32768) == (1/2048)*(1/256)

// Explicit drain: guarantees all global_load_lds DMA + ds_writes landed before
// the barrier. R17 relied on hipcc emitting this implicitly -- it sometimes
// doesn't (intermittent race). Must precede EVERY barrier whose consumers read
// gll16-written LDS.
#define DRAIN_SYNC() do { \
    asm volatile("s_waitcnt vmcnt(0) lgkmcnt(0)" ::: "memory"); \
    __syncthreads(); \
  } while (0)

static __device__ __forceinline__ float ftanh(float x) {
  float e = __builtin_amdgcn_exp2f(x * 2.885390081777927f);
  return 1.0f - 2.0f * __builtin_amdgcn_rcpf(e + 1.0f);
}
static __device__ __forceinline__ unsigned short bf16_rn(float f) {
  unsigned u = __float_as_uint(f);
  u += 0x7FFFu + ((u >> 16) & 1u);
  return (unsigned short)(u >> 16);
}
// x ~= hi/sc + lo/(sc*losc); rne via magic-add. Proven round 6.
static __device__ __forceinline__ void quant2(float x, float sc, float inv, float losc,
                                              int& hi, int& lo) {
  float t  = __builtin_fmaf(x, sc, 12582912.0f);
  hi = __float_as_int(t) - 0x4B400000;
  float hf = t - 12582912.0f;
  float r  = __builtin_fmaf(hf, -inv, x);
  float t2 = __builtin_fmaf(r, losc, 12582912.0f);
  lo = __float_as_int(t2) - 0x4B400000;
}
static __device__ __forceinline__ void gll16(const void* g, void* l) {
  __builtin_amdgcn_global_load_lds((const __attribute__((address_space(1))) unsigned int*)g,
                                   (__attribute__((address_space(3))) unsigned int*)l, 16, 0, 0);
}
#define MFMA_I8(ACC, A, B) \
  asm("v_mfma_i32_32x32x32_i8 %0, %1, %2, %0" : "+v"(ACC) : "v"(A), "v"(B))

// ---------------------------------------------------------------------------
// prep_w (verbatim round 6): pack W into chunked global_load_lds-ready streams.
// B1 per chunk kc (64KB): [Q-hi 16KB][Q-lo 16KB][V-bf16 32KB]
//   Q: byte = kc*65536 + sel*16384 + (nt*64+lane)*16 + j
//      value W[col = nt*32+(lane&31)][k = kc*32+(lane>>5)*16+j]
//   V: byte = kc*65536 + 32768 + ((nt*2+ks)*64+lane)*16 + j*2 (8 bf16)
// B2 per chunk (32KB): [K-hi 16KB][K-lo 16KB], same scheme.
// ---------------------------------------------------------------------------
__global__ void prep_w(const float* __restrict__ Wq, const float* __restrict__ Wk,
                       const float* __restrict__ Wv,
                       char* __restrict__ B1, char* __restrict__ B2) {
  int gid = blockIdx.x * 256 + threadIdx.x;   // 0..98303
  if (gid < 65536) {
    int chunk = gid >> 12, g = gid & 4095;
    char* dst = B1 + chunk * 65536 + g * 16;
    if (g < 2048) {
      int sel = g >> 10;
      int gg = g & 1023, nt = gg >> 6, lane = gg & 63;
      const float* src = Wq + (size_t)(nt * 32 + (lane & 31)) * 512 + chunk * 32 + (lane >> 5) * 16;
      union { char b[16]; i32x4 v; } ob;
#pragma unroll
      for (int j = 0; j < 16; ++j) {
        int h, l; quant2(src[j], 256.f, 1.f / 256.f, 32768.f, h, l);
        ob.b[j] = (char)(sel ? l : h);
      }
      *(i32x4*)dst = ob.v;
    } else {
      int gg = g - 2048, nt = gg >> 7, ks = (gg >> 6) & 1, lane = gg & 63;
      const float* src = Wv + (size_t)(nt * 32 + (lane & 31)) * 512 + chunk * 32 + ks * 16 + (lane >> 5) * 8;
      union { unsigned short s[8]; i32x4 v; } ob;
#pragma unroll
      for (int j = 0; j < 8; ++j) ob.s[j] = bf16_rn(src[j]);
      *(i32x4*)dst = ob.v;
    }
  } else {
    int gid2 = gid - 65536;
    int chunk = gid2 >> 11, g = gid2 & 2047;
    char* dst = B2 + chunk * 32768 + g * 16;
    int sel = g >> 10, gg = g & 1023, nt = gg >> 6, lane = gg & 63;
    const float* src = Wk + (size_t)(nt * 32 + (lane & 31)) * 512 + chunk * 32 + (lane >> 5) * 16;
    union { char b[16]; i32x4 v; } ob;
#pragma unroll
    for (int j = 0; j < 16; ++j) {
      int h, l; quant2(src[j], 256.f, 1.f / 256.f, 32768.f, h, l);
      ob.b[j] = (char)(sel ? l : h);
    }
    *(i32x4*)dst = ob.v;
  }
}

// ---- A-staging (verbatim R6/R14): thread (row=tid>>3, d0=(tid&7)*4), 64x32
// chunk -> i8 hi/lo frag planes (4KB: hi mt0@0, mt1@1024; lo @2048/3072). ----
static __device__ __forceinline__ void stageAi8(char* Ab, int row, int d0, float4 xv) {
  const int mt = row >> 5, l31 = row & 31;
  int h0, l0, h1, l1, h2, l2, h3, l3;
  quant2(xv.x, 16.f, 0.0625f, 2048.f, h0, l0);
  quant2(xv.y, 16.f, 0.0625f, 2048.f, h1, l1);
  quant2(xv.z, 16.f, 0.0625f, 2048.f, h2, l2);
  quant2(xv.w, 16.f, 0.0625f, 2048.f, h3, l3);
  unsigned wh = (h0 & 255) | ((h1 & 255) << 8) | ((h2 & 255) << 16) | ((unsigned)(h3 & 255) << 24);
  unsigned wl = (l0 & 255) | ((l1 & 255) << 8) | ((l2 & 255) << 16) | ((unsigned)(l3 & 255) << 24);
  const int lane8 = (d0 >> 4) * 32 + l31, j = d0 & 15;
  *(unsigned*)(Ab + (mt * 64 + lane8) * 16 + j) = wh;
  *(unsigned*)(Ab + 2048 + (mt * 64 + lane8) * 16 + j) = wl;
}
// bf16 (V) frag planes (4KB, (mt*2+ks) planes) -- verbatim R6/R14 stageAv.
static __device__ __forceinline__ void stageAv(char* Ab, int row, int d0, float4 xv) {
  const int mt = row >> 5, l31 = row & 31;
  unsigned long long b0 = bf16_rn(xv.x), b1 = bf16_rn(xv.y), b2 = bf16_rn(xv.z), b3 = bf16_rn(xv.w);
  unsigned long long vv = b0 | (b1 << 16) | (b2 << 32) | (b3 << 48);
  const int ks = d0 >> 4, rem = d0 & 15, hs8 = rem >> 3, j8 = rem & 7;
  *(unsigned long long*)(Ab + ((mt * 2 + ks) * 64 + hs8 * 32 + l31) * 16 + j8 * 2) = vv;
}

// ---------------------------------------------------------------------------
// pass_q: Q (i8 2-term, colsum). R14 geometry (64r x 512c, 1024 thr, 16 waves
// as 2mt x 8ng, wave = 32r x 64c) with double-length barrier intervals:
// 8 intervals x 2 chunks (K=64), ONE explicit-drain barrier per interval.
// ---------------------------------------------------------------------------
__global__ __launch_bounds__(1024, 4) void pass_q(
    const float* __restrict__ x, const char* __restrict__ B1,
    const float* __restrict__ bq, float* __restrict__ qpart) {
  extern __shared__ char smem[];
  char* Bb0 = smem;            char* Bb1 = smem + 65536;    // B dbuf 2x64KB
  char* Ab0 = smem + 131072;   char* Ab1 = smem + 139264;   // A dbuf 2x8KB
  float* redq = (float*)(smem + 147456);                    // [2][512] = 4KB

  const int tid = threadIdx.x, lane = tid & 63, w = tid >> 6;  // w 0..15
  const int l31 = lane & 31;
  const int mt = w >> 3, ng = w & 7;
  const int tile = blockIdx.x;
  const int stag = tile & 7;                               // interval stagger
  const int row = tid >> 3, d0 = (tid & 7) * 4;            // staging (tid<512)
  const float* gxr = x + ((size_t)tile * 64 + row) * 512 + d0;

  i32x16 q1[2] = {}, q2[2] = {};

  // prologue: stage interval stag's 2 chunks into Ab0; issue its B into Bb0
  if (tid < 512) {
    float4 xa = *(const float4*)(gxr + (2 * stag) * 32);
    float4 xb = *(const float4*)(gxr + (2 * stag + 1) * 32);
    stageAi8(Ab0, row, d0, xa);
    stageAi8(Ab0 + 4096, row, d0, xb);
  }
  {
    const char* s0 = B1 + (size_t)(2 * stag) * 65536 + tid * 16;
    const char* s1 = B1 + (size_t)(2 * stag + 1) * 65536 + tid * 16;
    gll16(s0, Bb0 + tid * 16);
    gll16(s0 + 16384, Bb0 + 16384 + tid * 16);
    gll16(s1, Bb0 + 32768 + tid * 16);
    gll16(s1 + 16384, Bb0 + 49152 + tid * 16);
  }

#pragma unroll 1
  for (int i = 0; i < 8; ++i) {
    const int p = i & 1;
    char* Bc = p ? Bb1 : Bb0;  char* Bn = p ? Bb0 : Bb1;
    char* Ac = p ? Ab1 : Ab0;  char* An = p ? Ab0 : Ab1;
    DRAIN_SYNC();                        // guaranteed: Bc/Ac contents landed
    const int ni = (i + 1 + stag) & 7;   // next interval
    if (i < 7) {
      const char* s0 = B1 + (size_t)(2 * ni) * 65536 + tid * 16;
      const char* s1 = B1 + (size_t)(2 * ni + 1) * 65536 + tid * 16;
      gll16(s0, Bn + tid * 16);
      gll16(s0 + 16384, Bn + 16384 + tid * 16);
      gll16(s1, Bn + 32768 + tid * 16);
      gll16(s1 + 16384, Bn + 49152 + tid * 16);
    }
    if (tid < 512 && i < 7) {
      float4 xa = *(const float4*)(gxr + (2 * ni) * 32);
      float4 xb = *(const float4*)(gxr + (2 * ni + 1) * 32);
      stageAi8(An, row, d0, xa);
      stageAi8(An + 4096, row, d0, xb);
    }

    const int lo16 = lane * 16;
#pragma unroll
    for (int sub = 0; sub < 2; ++sub) {
      const char* Ap = Ac + sub * 4096;
      const char* Bp = Bc + sub * 32768;
      i32x4 ah = *(const i32x4*)(Ap + mt * 1024 + lo16);
      i32x4 al = *(const i32x4*)(Ap + 2048 + mt * 1024 + lo16);
#pragma unroll
      for (int nn = 0; nn < 2; ++nn) {
        const int nt = ng * 2 + nn;
        i32x4 bh = *(const i32x4*)(Bp + nt * 1024 + lo16);
        i32x4 bl = *(const i32x4*)(Bp + 16384 + nt * 1024 + lo16);
        MFMA_I8(q1[nn], ah, bh);
        MFMA_I8(q2[nn], ah, bl);
        MFMA_I8(q2[nn], al, bh);
      }
    }
  }

  // epilogue (verbatim R14): per-mt colsum partial -> fold across 2 mt-waves
#pragma unroll
  for (int nn = 0; nn < 2; ++nn) {
    const int col = (ng * 2 + nn) * 32 + l31;
    const float bc = bq[col];
    float cs = 0.f;
#pragma unroll
    for (int r = 0; r < 16; ++r)
      cs += ftanh(__builtin_fmaf((float)q1[nn][r], SC1,
                  __builtin_fmaf((float)q2[nn][r], SC2, bc)));
    cs += __shfl_xor(cs, 32);
    if (lane < 32) redq[mt * 512 + col] = cs;
  }
  __syncthreads();
  if (tid < 512) qpart[(size_t)tile * 512 + tid] = redq[tid] + redq[512 + tid];
}

// ---------------------------------------------------------------------------
// pass_v: V (bf16 1-term, rowsum). Same interval structure; B = V sub-regions.
// ---------------------------------------------------------------------------
__global__ __launch_bounds__(1024, 4) void pass_v(
    const float* __restrict__ x, const char* __restrict__ B1,
    const float* __restrict__ bv, float* __restrict__ svout) {
  extern __shared__ char smem[];
  char* Bb0 = smem;            char* Bb1 = smem + 65536;
  char* Ab0 = smem + 131072;   char* Ab1 = smem + 139264;
  float* redv = (float*)(smem + 147456);                    // [8][64] = 2KB

  const int tid = threadIdx.x, lane = tid & 63, w = tid >> 6;
  const int l31 = lane & 31, hs = lane >> 5;
  const int mt = w >> 3, ng = w & 7;
  const int tile = blockIdx.x;
  const int stag = tile & 7;
  const int row = tid >> 3, d0 = (tid & 7) * 4;
  const float* gxr = x + ((size_t)tile * 64 + row) * 512 + d0;

  f32x16 accv[2] = {};

  if (tid < 512) {
    float4 xa = *(const float4*)(gxr + (2 * stag) * 32);
    float4 xb = *(const float4*)(gxr + (2 * stag + 1) * 32);
    stageAv(Ab0, row, d0, xa);
    stageAv(Ab0 + 4096, row, d0, xb);
  }
  {
    const char* s0 = B1 + (size_t)(2 * stag) * 65536 + 32768 + tid * 16;
    const char* s1 = B1 + (size_t)(2 * stag + 1) * 65536 + 32768 + tid * 16;
    gll16(s0, Bb0 + tid * 16);
    gll16(s0 + 16384, Bb0 + 16384 + tid * 16);
    gll16(s1, Bb0 + 32768 + tid * 16);
    gll16(s1 + 16384, Bb0 + 49152 + tid * 16);
  }

#pragma unroll 1
  for (int i = 0; i < 8; ++i) {
    const int p = i & 1;
    char* Bc = p ? Bb1 : Bb0;  char* Bn = p ? Bb0 : Bb1;
    char* Ac = p ? Ab1 : Ab0;  char* An = p ? Ab0 : Ab1;
    DRAIN_SYNC();
    const int ni = (i + 1 + stag) & 7;
    if (i < 7) {
      const char* s0 = B1 + (size_t)(2 * ni) * 65536 + 32768 + tid * 16;
      const char* s1 = B1 + (size_t)(2 * ni + 1) * 65536 + 32768 + tid * 16;
      gll16(s0, Bn + tid * 16);
      gll16(s0 + 16384, Bn + 16384 + tid * 16);
      gll16(s1, Bn + 32768 + tid * 16);
      gll16(s1 + 16384, Bn + 49152 + tid * 16);
    }
    if (tid < 512 && i < 7) {
      float4 xa = *(const float4*)(gxr + (2 * ni) * 32);
      float4 xb = *(const float4*)(gxr + (2 * ni + 1) * 32);
      stageAv(An, row, d0, xa);
      stageAv(An + 4096, row, d0, xb);
    }

    const int lo16 = lane * 16;
#pragma unroll
    for (int sub = 0; sub < 2; ++sub) {
      const char* Ap = Ac + sub * 4096;
      const char* Bp = Bc + sub * 32768;
#pragma unroll
      for (int ks = 0; ks < 2; ++ks) {
        short8 av = *(const short8*)(Ap + (mt * 2 + ks) * 1024 + lo16);
#pragma unroll
        for (int nn = 0; nn < 2; ++nn) {
          const int nt = ng * 2 + nn;
          short8 bvf = *(const short8*)(Bp + (nt * 2 + ks) * 1024 + lo16);
          accv[nn] = __builtin_amdgcn_mfma_f32_32x32x16_bf16(av, bvf, accv[nn], 0, 0, 0);
        }
      }
    }
  }

  // epilogue (verbatim R14)
  const float bv0 = bv[(ng * 2 + 0) * 32 + l31];
  const float bv1 = bv[(ng * 2 + 1) * 32 + l31];
  __syncthreads();
#pragma unroll
  for (int r = 0; r < 16; ++r) {
    float s = ftanh(accv[0][r] + bv0) + ftanh(accv[1][r] + bv1);
#pragma unroll
    for (int off = 1; off <= 16; off <<= 1) s += __shfl_xor(s, off);
    if (l31 == 0) redv[ng * 64 + mt * 32 + (r & 3) + 8 * (r >> 2) + 4 * hs] = s;
  }
  __syncthreads();
  if (tid < 64) {
    float s = 0.f;
#pragma unroll
    for (int j = 0; j < 8; ++j) s += redv[j * 64 + tid];
    svout[(size_t)tile * 64 + tid] = s;
  }
}

// ---------------------------------------------------------------------------
// pass_k: K (i8 2-term, rowsum * q_sum). Same interval structure; B from B2.
// ---------------------------------------------------------------------------
__global__ __launch_bounds__(1024, 4) void pass_k(
    const float* __restrict__ x, const char* __restrict__ B2,
    const float* __restrict__ bk, const float* __restrict__ q_sum,
    float* __restrict__ scores) {
  extern __shared__ char smem[];
  char* Bb0 = smem;            char* Bb1 = smem + 65536;
  char* Ab0 = smem + 131072;   char* Ab1 = smem + 139264;
  float* redk = (float*)(smem + 147456);                    // [8][64] = 2KB

  const int tid = threadIdx.x, lane = tid & 63, w = tid >> 6;
  const int l31 = lane & 31, hs = lane >> 5;
  const int mt = w >> 3, ng = w & 7;
  const int tile = blockIdx.x;
  const int stag = tile & 7;
  const int row = tid >> 3, d0 = (tid & 7) * 4;
  const float* gxr = x + ((size_t)tile * 64 + row) * 512 + d0;

  i32x16 k1[2] = {}, k2[2] = {};

  if (tid < 512) {
    float4 xa = *(const float4*)(gxr + (2 * stag) * 32);
    float4 xb = *(const float4*)(gxr + (2 * stag + 1) * 32);
    stageAi8(Ab0, row, d0, xa);
    stageAi8(Ab0 + 4096, row, d0, xb);
  }
  {
    const char* s0 = B2 + (size_t)(2 * stag) * 32768 + tid * 16;
    const char* s1 = B2 + (size_t)(2 * stag + 1) * 32768 + tid * 16;
    gll16(s0, Bb0 + tid * 16);
    gll16(s0 + 16384, Bb0 + 16384 + tid * 16);
    gll16(s1, Bb0 + 32768 + tid * 16);
    gll16(s1 + 16384, Bb0 + 49152 + tid * 16);
  }

#pragma unroll 1
  for (int i = 0; i < 8; ++i) {
    const int p = i & 1;
    char* Bc = p ? Bb1 : Bb0;  char* Bn = p ? Bb0 : Bb1;
    char* Ac = p ? Ab1 : Ab0;  char* An = p ? Ab0 : Ab1;
    DRAIN_SYNC();
    const int ni = (i + 1 + stag) & 7;
    if (i < 7) {
      const char* s0 = B2 + (size_t)(2 * ni) * 32768 + tid * 16;
      const char* s1 = B2 + (size_t)(2 * ni + 1) * 32768 + tid * 16;
      gll16(s0, Bn + tid * 16);
      gll16(s0 + 16384, Bn + 16384 + tid * 16);
      gll16(s1, Bn + 32768 + tid * 16);
      gll16(s1 + 16384, Bn + 49152 + tid * 16);
    }
    if (tid < 512 && i < 7) {
      float4 xa = *(const float4*)(gxr + (2 * ni) * 32);
      float4 xb = *(const float4*)(gxr + (2 * ni + 1) * 32);
      stageAi8(An, row, d0, xa);
      stageAi8(An + 4096, row, d0, xb);
    }

    const int lo16 = lane * 16;
#pragma unroll
    for (int sub = 0; sub < 2; ++sub) {
      const char* Ap = Ac + sub * 4096;
      const char* Bp = Bc + sub * 32768;
      i32x4 ah = *(const i32x4*)(Ap + mt * 1024 + lo16);
      i32x4 al = *(const i32x4*)(Ap + 2048 + mt * 1024 + lo16);
#pragma unroll
      for (int nn = 0; nn < 2; ++nn) {
        const int nt = ng * 2 + nn;
        i32x4 bh = *(const i32x4*)(Bp + nt * 1024 + lo16);
        i32x4 bl = *(const i32x4*)(Bp + 16384 + nt * 1024 + lo16);
        MFMA_I8(k1[nn], ah, bh);
        MFMA_I8(k2[nn], ah, bl);
        MFMA_I8(k2[nn], al, bh);
      }
    }
  }

  // epilogue (verbatim R14)
  const int b = tile >> 6;   // 64 tiles per batch
  const int c0 = (ng * 2 + 0) * 32 + l31, c1 = (ng * 2 + 1) * 32 + l31;
  const float qs0 = q_sum[b * 512 + c0], qs1 = q_sum[b * 512 + c1];
  const float bk0 = bk[c0], bk1 = bk[c1];
  __syncthreads();
#pragma unroll
  for (int r = 0; r < 16; ++r) {
    float p0 = __builtin_fmaf((float)k1[0][r], SC1,
               __builtin_fmaf((float)k2[0][r], SC2, bk0));
    float p1 = __builtin_fmaf((float)k1[1][r], SC1,
               __builtin_fmaf((float)k2[1][r], SC2, bk1));
    float s = ftanh(p0) * qs0 + ftanh(p1) * qs1;
#pragma unroll
    for (int off = 1; off <= 16; off <<= 1) s += __shfl_xor(s, off);
    if (l31 == 0) redk[ng * 64 + mt * 32 + (r & 3) + 8 * (r >> 2) + 4 * hs] = s;
  }
  __syncthreads();
  if (tid < 64) {
    float s = 0.f;
#pragma unroll
    for (int j = 0; j < 8; ++j) s += redk[j * 64 + tid];
    scores[(size_t)tile * 64 + tid] = s;
  }
}

// q_sum[b][e] = sum of the batch's 64 tile partials (64-row tiles)
__global__ void reduce_q(const float* __restrict__ qpart, float* __restrict__ q_sum) {
  int b = blockIdx.x, e = threadIdx.x;
  const float* p = qpart + (size_t)b * 64 * 512 + e;
  float s = 0.f;
#pragma unroll 4
  for (int j = 0; j < 64; ++j) s += p[j * 512];
  q_sum[b * 512 + e] = s;
}

// per-batch masked softmax over scaled scores, times sv
__global__ void softmax_out(const float* __restrict__ scores,
                            const float* __restrict__ sv,
                            const int* __restrict__ lens,
                            float* __restrict__ out) {
  const int b = blockIdx.x, tid = threadIdx.x;   // 256
  const int lane = tid & 63, wid = tid >> 6;
  const int len = lens[b];
  const float scale = 0.04419417382415922f;      // 1/sqrt(512)
  __shared__ float sb[4], sb2[4];

  float sreg[16];
  const float* sc = scores + (size_t)b * 4096;
#pragma unroll
  for (int j = 0; j < 16; ++j) sreg[j] = sc[tid + j * 256] * scale;

  float m = -1e30f;
#pragma unroll
  for (int j = 0; j < 16; ++j)
    if (tid + j * 256 < len) m = fmaxf(m, sreg[j]);
#pragma unroll
  for (int off = 32; off >= 1; off >>= 1) m = fmaxf(m, __shfl_xor(m, off));
  if (lane == 0) sb[wid] = m;
  __syncthreads();
  m = fmaxf(fmaxf(sb[0], sb[1]), fmaxf(sb[2], sb[3]));

  float s = 0.f;
#pragma unroll
  for (int j = 0; j < 16; ++j)
    if (tid + j * 256 < len) s += expf(sreg[j] - m);
#pragma unroll
  for (int off = 32; off >= 1; off >>= 1) s += __shfl_xor(s, off);
  if (lane == 0) sb2[wid] = s;
  __syncthreads();
  const float inv = 1.f / (sb2[0] + sb2[1] + sb2[2] + sb2[3]);

  const float* svb = sv + (size_t)b * 4096;
  float* ob = out + (size_t)b * 4096;
#pragma unroll
  for (int j = 0; j < 16; ++j) {
    int l = tid + j * 256;
    ob[l] = (l < len) ? svb[l] * expf(sreg[j] - m) * inv : 0.0f;
  }
}

extern "C" void kernel_launch(void* const* d_in, const int* in_sizes, int n_in,
                              void* d_out, int out_size, void* d_ws, size_t ws_size,
                              hipStream_t stream) {
  const float* x  = (const float*)d_in[0];
  const float* Wk = (const float*)d_in[1];
  const float* bk = (const float*)d_in[2];
  const float* Wq = (const float*)d_in[3];
  const float* bq = (const float*)d_in[4];
  const float* Wv = (const float*)d_in[5];
  const float* bv = (const float*)d_in[6];
  const int* lens = (const int*)d_in[7];
  float* out = (float*)d_out;

  char* ws = (char*)d_ws;
  char*  B1     = ws;                          // 1 MB   (Q+V W pack)
  char*  B2     = ws + 1048576;                // 512 KB (K W pack)
  float* qpart  = (float*)(ws + 1572864);      // [1024][512] f32 = 2 MB
  float* q_sum  = (float*)(ws + 3670016);      // [16][512] = 32 KB
  float* svbuf  = (float*)(ws + 3702784);      // [65536] = 256 KB
  float* scores = (float*)(ws + 3964928);      // [65536] = 256 KB

  prep_w<<<384, 256, 0, stream>>>(Wq, Wk, Wv, B1, B2);
  pass_q<<<1024, 1024, 151552, stream>>>(x, B1, bq, qpart);
  pass_v<<<1024, 1024, 149504, stream>>>(x, B1, bv, svbuf);
  reduce_q<<<16, 512, 0, stream>>>(qpart, q_sum);
  pass_k<<<1024, 1024, 149504, stream>>>(x, B2, bk, q_sum, scores);
  softmax_out<<<16, 256, 0, stream>>>(scores, svbuf, lens, out);
}